// Round 12
// baseline (300.732 us; speedup 1.0000x reference)
//
#include <hip/hip_runtime.h>
#include <stdint.h>

typedef _Float16 f16;
typedef f16  f16x8 __attribute__((ext_vector_type(8)));
typedef f16  f16x4 __attribute__((ext_vector_type(4)));
typedef f16  f16x2 __attribute__((ext_vector_type(2)));
typedef float f32x4 __attribute__((ext_vector_type(4)));

#define W 512
#define H 512
#define KS 11
#define NW 4                // waves per block
#define NBLK 6144           // 48 slices * 16 ty * 8 tx (64x32 out per block)
#define NLINES 256          // spread accumulator lines (64 B apart)
#define C1_SSIM 0.0001f
#define C2_SSIM 0.0009f
#define NTOTAL 12582912.0f

// LDS: f16 window 48 rows x 80 cols per image (160 B row stride; R4-verified
// bank-uniform layout, measured 0 conflicts).  2 images = 15.36 KB ->
// 8 blocks/CU (launch_bounds(256,8)) = 32 waves/CU = HW occupancy cap.
#define LSTRIDE 80          // f16 units
#define IMGF16 3840         // 48*80

// Normalized separable Gaussian (ksize=11, sigma=1.5), f32 master copy.
__device__ __constant__ const float GW[KS] = {
    1.02838e-3f, 7.59876e-3f, 3.600076e-2f, 1.0936069e-1f, 2.1300554e-1f,
    2.6601172e-1f,
    2.1300554e-1f, 1.0936069e-1f, 3.600076e-2f, 7.59876e-3f, 1.02838e-3f
};

__device__ inline float ssim_px(float ux, float uy, float uxx, float uyy, float uxy) {
    const float uxuy = ux * uy;
    const float a = 2.f * uxuy + C1_SSIM;
    const float b = 2.f * (uxy - uxuy) + C2_SSIM;
    const float c = ux * ux + uy * uy + C1_SSIM;
    const float d = (uxx - ux * ux) + (uyy - uy * uy) + C2_SSIM;
    return (a * b) * __builtin_amdgcn_rcpf(c * d);
}

struct __attribute__((aligned(16))) F4 { float x, y, z, w; };

__device__ __forceinline__ f16x8 pack8(const float v[8]) {
    f16x8 r;
    #pragma unroll
    for (int p = 0; p < 4; ++p) {
        const f16x2 h = __builtin_bit_cast(
            f16x2, __builtin_amdgcn_cvt_pkrtz(v[2 * p], v[2 * p + 1]));
        r[2 * p]     = h[0];
        r[2 * p + 1] = h[1];
    }
    return r;
}

// R4-verified guarded 8-float load (aligned dwordx4 pair fast path).
__device__ __forceinline__ void load8f(const float* __restrict__ base, int ry,
                                       int xs, float v[8]) {
    if ((unsigned)ry < (unsigned)H && (unsigned)xs <= (unsigned)(W - 8)) {
        const float* r = base + ((size_t)ry << 9) + xs;
        const F4 a = *(const F4*)r;
        const F4 b = *(const F4*)(r + 4);
        v[0] = a.x; v[1] = a.y; v[2] = a.z; v[3] = a.w;
        v[4] = b.x; v[5] = b.y; v[6] = b.z; v[7] = b.w;
    } else {
        #pragma unroll
        for (int j = 0; j < 8; ++j) v[j] = 0.f;
    }
}

// MAX-OCCUPANCY variant (the one untried cell after 11 rounds): every prior
// structure (reg/DMA staging, bulk/phased/persistent drain, 19-52% occ) sat
// at ~46 us with waves ~80% stalled and NO pipe above 42% -- latency-bound
// with too few resident waves.  This kernel: 64x32 out tile, f16 reg-staged
// LDS (15.4 KB, R4-verified path: VGPR 40, 0 bank conflicts) -> 8 blocks/CU
// = 32 waves/CU (HW cap).  XCD swizzle gives each XCD contiguous (z,ty,tx)
// runs, tx-fastest: the 8 tx tiles of one row-band co-resident on one XCD
// -> full 2-KB DRAM rows fetched once into that XCD's L2 (R11's ty-fastest
// swizzle inverted; it was a regression).  Compute = verbatim R11-verified
// 3-group fragment algebra (absmax 0.0).  Finisher fused via last-block
// counter (parallel atomic-fetch reduce) -- one launch fewer.
__global__ __launch_bounds__(256, 8)
void ssim_main(const float* __restrict__ simg, const float* __restrict__ timg,
               float* __restrict__ ws, float* __restrict__ out) {
    __shared__ __align__(16) f16 lds[2][IMGF16];
    __shared__ float red[NW];
    __shared__ int lastflag;

    const int tid  = threadIdx.x;
    const int w    = tid >> 6;
    const int lane = tid & 63;
    const int n    = lane & 15;
    const int q    = lane >> 4;

    // Bijective XCD swizzle (6144 % 8 == 0): XCD x owns L in [768x, 768x+768)
    // = contiguous (z,ty,tx) with tx fastest.
    const int bid = blockIdx.x;
    const int L   = (bid & 7) * (NBLK / 8) + (bid >> 3);
    const int z   = L >> 7;               // 48 slices (16 batch * 3 ch)
    const int rr  = L & 127;
    const int ty  = rr >> 3;              // 16 x 32-row bands
    const int tx  = rr & 7;

    const float* sp = simg + ((size_t)z << 18);
    const float* tp = timg + ((size_t)z << 18);
    const int ybase = (ty << 5) - 5;      // stored row 0 (48 rows)
    const int xbase = (tx << 6) - 8;      // stored col 0 (80 cols, aligned)

    // ---- PHASE 1: reg-staged f16 LDS fill (R4-verified mapping) ----
    // 960 tasks of 8 floats: img = u>=480, uu = u%480, row lr = uu/10,
    // 8-col seg sg = uu%10.  4 rounds of 256 threads (tail 192).
    #pragma unroll
    for (int it = 0; it < 4; ++it) {
        const int u = (it << 8) + tid;
        if (it < 3 || u < 960) {
            const int img = (u >= 480) ? 1 : 0;
            const int uu  = img ? (u - 480) : u;
            const int lr  = (uu * 205) >> 11;       // uu/10 for uu<800
            const int sg  = uu - lr * 10;
            float v[8];
            load8f(img ? tp : sp, ybase + lr, xbase + (sg << 3), v);
            *(f16x8*)&lds[img][lr * LSTRIDE + (sg << 3)] = pack8(v);
        }
    }

    // Fragment setup (verified algebra; hconv band d = k-n-3 absorbs the
    // -8-col aligned window).
    f16x8 af;
    #pragma unroll
    for (int j = 0; j < 8; ++j) {
        const int k = (q << 3) + j;
        const int d = k - n - 3;
        af[j] = (d >= 0 && d < KS) ? (f16)GW[d] : (f16)0.f;
    }
    f16x4 a1v, a2v;
    #pragma unroll
    for (int j = 0; j < 4; ++j) {
        const int k  = (q << 2) + j;
        const int d1 = k - n;
        const int d2 = k + 16 - n;
        a1v[j] = (d1 >= 0 && d1 < KS) ? (f16)GW[d1] : (f16)0.f;
        a2v[j] = (d2 >= 0 && d2 < KS) ? (f16)GW[d2] : (f16)0.f;
    }

    __syncthreads();

    // ---- PHASE 2: compute (verbatim R11-verified 3-group pipeline) ----
    union H4 { f16x4 v4; f16x2 v2[2]; };
    const int coff = (w << 4) + (q << 3);   // f16 col offset: 16w + 8q
    const f16* lss = &lds[0][coff];
    const f16* lts = &lds[1][coff];

    f16x4 ph[2][5];
    float sum = 0.f;

    #pragma unroll
    for (int g = 0; g < 3; ++g) {
        const int ro = ((g << 4) + n) * LSTRIDE;
        const f16x8 sf = *(const f16x8*)(lss + ro);
        const f16x8 tf = *(const f16x8*)(lts + ro);
        const int pb = g & 1;
        #pragma unroll
        for (int c = 0; c < 5; ++c) {
            f16x8 ch;
            if      (c == 0) ch = sf;
            else if (c == 1) ch = tf;
            else if (c == 2) ch = sf * sf;
            else if (c == 3) ch = tf * tf;
            else             ch = sf * tf;
            const f32x4 zero = {0.f, 0.f, 0.f, 0.f};
            const f32x4 d = __builtin_amdgcn_mfma_f32_16x16x32_f16(ch, af, zero, 0, 0, 0);
            H4 u;
            u.v2[0] = __builtin_bit_cast(f16x2, __builtin_amdgcn_cvt_pkrtz(d[0], d[1]));
            u.v2[1] = __builtin_bit_cast(f16x2, __builtin_amdgcn_cvt_pkrtz(d[2], d[3]));
            ph[pb][c] = u.v4;              // lane-local: rows 4q..4q+3 at one col
        }
        if (g >= 1) {
            const int pa = pb ^ 1;        // vconv tile t = g-1 (out rows 16t..)
            f32x4 acc[5];
            #pragma unroll
            for (int c = 0; c < 5; ++c) {
                const f32x4 zero = {0.f, 0.f, 0.f, 0.f};
                f32x4 a = __builtin_amdgcn_mfma_f32_16x16x16f16(a2v, ph[pb][c], zero, 0, 0, 0);
                a = __builtin_amdgcn_mfma_f32_16x16x16f16(a1v, ph[pa][c], a, 0, 0, 0);
                acc[c] = a;
            }
            #pragma unroll
            for (int rg = 0; rg < 4; ++rg)
                sum += ssim_px(acc[0][rg], acc[1][rg], acc[2][rg],
                               acc[3][rg], acc[4][rg]);
        }
    }

    // ---- Wave reduce, block reduce, spread atomic, fused finisher ----
    #pragma unroll
    for (int off = 32; off > 0; off >>= 1)
        sum += __shfl_down(sum, off, 64);
    if (lane == 0) red[w] = sum;
    __syncthreads();
    if (tid == 0) {
        atomicAdd(&ws[(bid & (NLINES - 1)) << 4],
                  red[0] + red[1] + red[2] + red[3]);
        __threadfence();
        const unsigned old = atomicAdd((unsigned*)(ws + (NLINES << 4)), 1u);
        lastflag = (old == (unsigned)(NBLK - 1));
    }
    __syncthreads();
    if (lastflag) {
        __threadfence();
        // 256 threads fetch the 256 spread lines coherently (atomic fetch),
        // then block-reduce.
        float s = atomicAdd(&ws[tid << 4], 0.f);
        #pragma unroll
        for (int off = 32; off > 0; off >>= 1)
            s += __shfl_down(s, off, 64);
        if (lane == 0) red[w] = s;
        __syncthreads();
        if (tid == 0)
            out[0] = 1.f - (red[0] + red[1] + red[2] + red[3]) * (1.f / NTOTAL);
    }
}

extern "C" void kernel_launch(void* const* d_in, const int* in_sizes, int n_in,
                              void* d_out, int out_size, void* d_ws, size_t ws_size,
                              hipStream_t stream) {
    const float* s = (const float*)d_in[0];
    const float* t = (const float*)d_in[1];
    float* out = (float*)d_out;
    float* ws  = (float*)d_ws;   // 256 spread lines (4096 f32) + counter

    hipMemsetAsync(ws, 0, (NLINES * 16 + 16) * sizeof(float), stream);
    ssim_main<<<dim3(NBLK), 256, 0, stream>>>(s, t, ws, out);
}

// Round 13
// 130.945 us; speedup vs baseline: 2.2966x; 2.2966x over previous
//
#include <hip/hip_runtime.h>
#include <stdint.h>

typedef _Float16 f16;
typedef f16  f16x8 __attribute__((ext_vector_type(8)));
typedef f16  f16x4 __attribute__((ext_vector_type(4)));
typedef f16  f16x2 __attribute__((ext_vector_type(2)));
typedef float f32x4 __attribute__((ext_vector_type(4)));

#define W 512
#define H 512
#define KS 11
#define NW 8                // waves per block (512 threads)
#define NBLK 512            // persistent: 2 blocks/CU, 12 tiles each
#define NITER 12            // 6144 tiles / 512 blocks
#define NLINES 256          // spread accumulator lines (64 B apart)
#define C1_SSIM 0.0001f
#define C2_SSIM 0.0009f
#define NTOTAL 12582912.0f

// Tile = 64x32 outputs; window 80 cols x 48 rows f32 per image (320 B row
// stride) = 15 x 1-KB DMA chunks per image, 30 per tile.  One buffer =
// 30.72 KB; double-buffered = 61.44 KB -> 2 blocks/CU (16 waves/CU,
// 4 waves/SIMD) at launch_bounds(512,4) (VGPR cap 128: no spill, R12 lesson).
#define LCOLS 80
#define IMGF32 3840         // 48*80 f32 per image
#define TILEF32 7680        // both images
#define NCHUNK 30

// Normalized separable Gaussian (ksize=11, sigma=1.5), f32 master copy.
__device__ __constant__ const float GW[KS] = {
    1.02838e-3f, 7.59876e-3f, 3.600076e-2f, 1.0936069e-1f, 2.1300554e-1f,
    2.6601172e-1f,
    2.1300554e-1f, 1.0936069e-1f, 3.600076e-2f, 7.59876e-3f, 1.02838e-3f
};

__device__ inline float ssim_px(float ux, float uy, float uxx, float uyy, float uxy) {
    const float uxuy = ux * uy;
    const float a = 2.f * uxuy + C1_SSIM;
    const float b = 2.f * (uxy - uxuy) + C2_SSIM;
    const float c = ux * ux + uy * uy + C1_SSIM;
    const float d = (uxx - ux * ux) + (uyy - uy * uy) + C2_SSIM;
    return (a * b) * __builtin_amdgcn_rcpf(c * d);
}

__device__ __forceinline__ f16x8 pack84(f32x4 a, f32x4 b) {
    f16x8 r;
    f16x2 h;
    h = __builtin_bit_cast(f16x2, __builtin_amdgcn_cvt_pkrtz(a[0], a[1]));
    r[0] = h[0]; r[1] = h[1];
    h = __builtin_bit_cast(f16x2, __builtin_amdgcn_cvt_pkrtz(a[2], a[3]));
    r[2] = h[0]; r[3] = h[1];
    h = __builtin_bit_cast(f16x2, __builtin_amdgcn_cvt_pkrtz(b[0], b[1]));
    r[4] = h[0]; r[5] = h[1];
    h = __builtin_bit_cast(f16x2, __builtin_amdgcn_cvt_pkrtz(b[2], b[3]));
    r[6] = h[0]; r[7] = h[1];
    return r;
}

// DMA-stage one 64x32 tile (R11-verified mapping): chunk c (0..29):
// img=c>=15, cc=c%15; per-lane 16 B at off=cc*1024+lane*16 -> row=off/320
// (t16=off/64<240: row=(t16*205)>>10), col-byte off%320.  OOB lanes
// redirect the GLOBAL source to a zeroed workspace line (LDS dest stays
// wave-uniform-linear).  8 waves: wave w owns chunks c=8k+w (waves 0..5:
// 4 chunks, waves 6,7: 3).  No destination registers -> the compiler
// cannot corrupt or sink this prefetch (fatal flaws of reg-staged R1-R4/R8).
__device__ __forceinline__ void issue_dma(const float* __restrict__ simg,
                                          const float* __restrict__ timg,
                                          const float* __restrict__ zb,
                                          int w, int lane, int T, float* ldsbase) {
    const int z  = T >> 7;                // 48 slices
    const int rr = T & 127;
    const int ty = rr >> 3;               // 16 x 32-row bands
    const int tx = rr & 7;
    const float* sp = simg + ((size_t)z << 18);
    const float* tp = timg + ((size_t)z << 18);
    const int ybase = (ty << 5) - 5;
    const int xbase = (tx << 6) - 8;
    #pragma unroll
    for (int k = 0; k < 4; ++k) {
        const int c = (k << 3) + w;
        if (c < NCHUNK) {                 // wave-uniform
            const int img = (c >= 15) ? 1 : 0;
            const int cc  = img ? (c - 15) : c;
            const int off = (cc << 10) + (lane << 4);
            const int t16 = off >> 6;                 // < 240
            const int row = (t16 * 205) >> 10;        // off/320
            const int colb = off - row * 320;
            const int ry   = ybase + row;
            const int gcol = xbase + (colb >> 2);
            const float* src = img ? tp : sp;
            const bool ok = ((unsigned)ry < (unsigned)H) &
                            ((unsigned)gcol <= (unsigned)(W - 4));
            const float* ga = ok ? (src + ((size_t)ry << 9) + gcol) : zb;
            void* ldst = (char*)ldsbase + img * (IMGF32 * 4) + (cc << 10);
            __builtin_amdgcn_global_load_lds(
                (const uint32_t __attribute__((address_space(1)))*)ga,
                (uint32_t __attribute__((address_space(3)))*)ldst,
                16, 0, 0);
        }
    }
}

// Compute one wave's share of a 64x32 tile: h = w>>2 picks the 16-out-row
// half (vconv tile h, consuming hconv groups h, h+1); cw = w&3 picks the
// 16-col slice.  Per wave: 2 hconv groups x 5 ch MFMA(16x16x32) + 5 vconv
// chains of 2 MFMA(16x16x16) + 4 ssim_px -- half R10's per-wave chain.
// Fragment algebra verbatim from the verified absmax-0.0 kernels: hconv
// band d=k-n-3 absorbs the -8-col aligned window; vconv a1v on group h,
// a2v on group h+1; lane-local packed rows feed the vconv B operand.
__device__ __forceinline__ float compute_part(const float* __restrict__ base,
                                              int coff, int n, int h,
                                              f16x8 af, f16x4 a1v, f16x4 a2v) {
    union H4 { f16x4 v4; f16x2 v2[2]; };
    const float* ls = base + coff;
    const float* lt = base + IMGF32 + coff;
    f16x4 ph[2][5];
    #pragma unroll
    for (int j = 0; j < 2; ++j) {
        const int ro = (((h + j) << 4) + n) * LCOLS;
        const f32x4 s0 = *(const f32x4*)(ls + ro);
        const f32x4 s1 = *(const f32x4*)(ls + ro + 4);
        const f32x4 t0 = *(const f32x4*)(lt + ro);
        const f32x4 t1 = *(const f32x4*)(lt + ro + 4);
        const f16x8 sf = pack84(s0, s1);
        const f16x8 tf = pack84(t0, t1);
        #pragma unroll
        for (int c = 0; c < 5; ++c) {
            f16x8 ch;
            if      (c == 0) ch = sf;
            else if (c == 1) ch = tf;
            else if (c == 2) ch = sf * sf;
            else if (c == 3) ch = tf * tf;
            else             ch = sf * tf;
            const f32x4 zero = {0.f, 0.f, 0.f, 0.f};
            const f32x4 d = __builtin_amdgcn_mfma_f32_16x16x32_f16(ch, af, zero, 0, 0, 0);
            H4 u;
            u.v2[0] = __builtin_bit_cast(f16x2, __builtin_amdgcn_cvt_pkrtz(d[0], d[1]));
            u.v2[1] = __builtin_bit_cast(f16x2, __builtin_amdgcn_cvt_pkrtz(d[2], d[3]));
            ph[j][c] = u.v4;               // lane-local: rows 4q..4q+3
        }
    }
    float sum = 0.f;
    f32x4 acc[5];
    #pragma unroll
    for (int c = 0; c < 5; ++c) {
        const f32x4 zero = {0.f, 0.f, 0.f, 0.f};
        f32x4 a = __builtin_amdgcn_mfma_f32_16x16x16f16(a2v, ph[1][c], zero, 0, 0, 0);
        a = __builtin_amdgcn_mfma_f32_16x16x16f16(a1v, ph[0][c], a, 0, 0, 0);
        acc[c] = a;
    }
    #pragma unroll
    for (int rg = 0; rg < 4; ++rg)
        sum += ssim_px(acc[0][rg], acc[1][rg], acc[2][rg],
                       acc[3][rg], acc[4][rg]);
    return sum;
}

// The one untested cell of the 12-round matrix: CONTINUOUS DMA (R10's
// counted-vmcnt persistent protocol -- the only structure with true
// stage||compute overlap) x 4 waves/SIMD (R10 was confounded at 2) x
// halved per-wave chains.  Bulk-drain high-occupancy variants failed
// because co-launched homogeneous blocks run in lockstep: they stage
// together and idle together at ANY occupancy.  Here tile t+1's 30 chunks
// are in flight during compute(t) in every block, and the 2 blocks/CU are
// not barrier-coupled to each other.
__global__ __launch_bounds__(512, 4)
void ssim_main(const float* __restrict__ simg, const float* __restrict__ timg,
               float* __restrict__ accum, const float* __restrict__ zbuf) {
    __shared__ __align__(16) float lds[2][TILEF32];   // 61.44 KB
    __shared__ float red[NW];

    const int tid  = threadIdx.x;
    const int w    = tid >> 6;
    const int lane = tid & 63;
    const int n    = lane & 15;
    const int q    = lane >> 4;
    const int h    = w >> 2;              // 16-row half
    const int cw   = w & 3;               // 16-col slice

    // Bijective XCD swizzle (512 % 8 == 0): co-resident blocks get
    // consecutive L (tx-fastest -> shared DRAM rows on one XCD's L2).
    const int bid = blockIdx.x;
    const int L   = (bid & 7) * (NBLK / 8) + (bid >> 3);

    // Prologue: stage tile 0 into buf0.
    issue_dma(simg, timg, zbuf, w, lane, L, &lds[0][0]);
    __builtin_amdgcn_sched_barrier(0);

    // Fragment setup under the in-flight DMA (verified algebra).
    f16x8 af;
    #pragma unroll
    for (int j = 0; j < 8; ++j) {
        const int k = (q << 3) + j;
        const int d = k - n - 3;
        af[j] = (d >= 0 && d < KS) ? (f16)GW[d] : (f16)0.f;
    }
    f16x4 a1v, a2v;
    #pragma unroll
    for (int j = 0; j < 4; ++j) {
        const int k  = (q << 2) + j;
        const int d1 = k - n;
        const int d2 = k + 16 - n;
        a1v[j] = (d1 >= 0 && d1 < KS) ? (f16)GW[d1] : (f16)0.f;
        a2v[j] = (d2 >= 0 && d2 < KS) ? (f16)GW[d2] : (f16)0.f;
    }

    const int coff = (cw << 4) + (q << 3);
    float sum = 0.f;

    for (int t = 0; t < NITER; ++t) {
        if (t < NITER - 1) {
            issue_dma(simg, timg, zbuf, w, lane, L + ((t + 1) << 9),
                      &lds[(t + 1) & 1][0]);
            __builtin_amdgcn_sched_barrier(0);
            // Counted wait: each wave owns <=4 chunks/tile; <=3 newest
            // outstanding => all of tile t's chunks have landed.
            asm volatile("s_waitcnt vmcnt(3)" ::: "memory");
        } else {
            asm volatile("s_waitcnt vmcnt(0)" ::: "memory");
        }
        __builtin_amdgcn_s_barrier();        // tile t visible to all waves
        __builtin_amdgcn_sched_barrier(0);

        sum += compute_part(&lds[t & 1][0], coff, n, h, af, a1v, a2v);

        __builtin_amdgcn_sched_barrier(0);
        __builtin_amdgcn_s_barrier();        // buffer free for next issue
    }

    // ---- Wave reduce, block reduce, one spread atomic per block ----
    #pragma unroll
    for (int off = 32; off > 0; off >>= 1)
        sum += __shfl_down(sum, off, 64);
    if (lane == 0) red[w] = sum;
    __syncthreads();
    if (tid == 0) {
        float bs = 0.f;
        #pragma unroll
        for (int i = 0; i < NW; ++i) bs += red[i];
        atomicAdd(&accum[(bid & (NLINES - 1)) << 4], bs);
    }
}

__global__ void ssim_final(const float* __restrict__ accum, float* __restrict__ out) {
    const int lane = threadIdx.x;
    float s = 0.f;
    #pragma unroll
    for (int i = 0; i < NLINES / 64; ++i)
        s += accum[((i << 6) + lane) << 4];
    #pragma unroll
    for (int off = 32; off > 0; off >>= 1)
        s += __shfl_down(s, off, 64);
    if (lane == 0) out[0] = 1.f - s * (1.f / NTOTAL);
}

extern "C" void kernel_launch(void* const* d_in, const int* in_sizes, int n_in,
                              void* d_out, int out_size, void* d_ws, size_t ws_size,
                              hipStream_t stream) {
    const float* s = (const float*)d_in[0];
    const float* t = (const float*)d_in[1];
    float* out   = (float*)d_out;
    float* accum = (float*)d_ws;                 // NLINES*16 floats = 16 KB
    const float* zbuf = accum + NLINES * 16;     // zeroed line for OOB DMA

    hipMemsetAsync(accum, 0, NLINES * 16 * sizeof(float) + 256, stream);
    ssim_main<<<dim3(NBLK), 512, 0, stream>>>(s, t, accum, zbuf);
    ssim_final<<<1, 64, 0, stream>>>(accum, out);
}